// Round 14
// baseline (911.412 us; speedup 1.0000x reference)
//
#include <hip/hip_runtime.h>
#include <hip/hip_bf16.h>

// Representation_32074815766664 — bf16 I/O (runtime-detected f32 fallback),
// bf16 MFMA internally, f32 accumulation/state.
//
// R24 change vs R23 (902 us — WIN, but fused1 359 us tripwire fired):
//  - R23 post-mortem: in-GEMM f32 conversion was fine; the cost was 4x
//    A-redundancy (each sample row read by 4 bx tiles -> 164 MB f32 HBM on
//    42 CUs; FETCH +7MB, MfmaUtil 36->29, samp outgrew lstm1's shadow).
//  - samp branch restructured: one 1024-thr block per 64-row tile (by=0..159)
//    computes the full 64x256 output. 16 waves = 4 row-tiles x 4 col-groups;
//    per kk: 1 A-frag (f32->bf16 on load) x 4 B-frags x 4 MFMAs. Waves
//    sharing a row-tile hit the same A addresses (L1 broadcast) -> unique A
//    traffic 41 MB once. W L2-resident. Same MFMA count, same load-or-zero
//    tail (MFMA whole-wave), same RNE cast.
//  - everything else FROZEN at R23 form.

typedef __bf16 bf16x8 __attribute__((ext_vector_type(8)));
typedef float f32x4 __attribute__((ext_vector_type(4)));

#define MROWS 10240
#define LDH1  552     // padded LDS stride (2-way bank aliasing only)
#define L1_ROWS 48
#define L1_BLOCKS 214 // ceil(10240/48)
#define SAMP_BASE 214 // 160 blocks (one per 64-row tile)
#define FEAT_BASE 374 // 40 blocks
#define FUSED_BLOCKS 414

// pf (canonical f32 params) offsets
#define PF_BIAS1   0
#define PF_BIAS2   2048
#define PF_CONDB   4096
#define PF_SAMPB   4352
#define PF_BCAT2   4608
#define PF_B3CAT   5120
#define PF_BN1G    5632
#define PF_BN1B    5888
#define PF_BN2G    6144
#define PF_BN2B    6656
#define PF_BN3G    7168
#define PF_BN3B    7424
#define PF_OW      7680
#define PF_OB      8192
#define PF_TOTAL   8194

// sig(x) = 1/(1+exp(-x)); robust without clamps: exp->inf => rcp->0.
__device__ __forceinline__ float fsig(float x) {
  return __builtin_amdgcn_rcpf(1.0f + __expf(-x));
}
// tanh(x) = 2*sig(2x) - 1; robust at both infinities.
__device__ __forceinline__ float ftanh(float x) {
  return fmaf(2.0f, __builtin_amdgcn_rcpf(1.0f + __expf(-2.0f * x)), -1.0f);
}
__device__ __forceinline__ bf16x8 bzero8() {
  bf16x8 z;
#pragma unroll
  for (int i = 0; i < 8; ++i) z[i] = (__bf16)0.0f;
  return z;
}
__device__ __forceinline__ float ld_in(const void* p, long i, int bf) {
  return bf ? (float)((const __bf16*)p)[i] : ((const float*)p)[i];
}

// ---------------- detect ----------------
__global__ void detect_kernel(const unsigned* __restrict__ masks, int* __restrict__ flag) {
  if (blockIdx.x == 0 && threadIdx.x == 0)
    *flag = (masks[0] == 0x3F803F80u) ? 1 : 0;
}

// ---------------- prep: canonicalize; w1s swizzled, w2s swizzled ----------------
// w1s: elem((cgt*17+kk)*4+g, lane, e) = w_aug1[g*512+cgt*16+(lane&15)][kk*32+(lane>>4)*8+e]
__global__ void prep_kernel(const int* __restrict__ flagp,
    const void* w_ih1, const void* w_hh1, const void* b_ih1, const void* b_hh1,
    const void* w_ih2, const void* w_hh2, const void* b_ih2, const void* b_hh2,
    const void* t1_w2, const void* t2_w2, const void* t1_b2, const void* t2_b2,
    const void* cond_w, const void* cond_b, const void* sample_w, const void* sample_b,
    const void* bn1_g, const void* bn1_b, const void* bn2_g, const void* bn2_b,
    const void* bn3_g, const void* bn3_b,
    const void* t1_w3, const void* t1_b3, const void* t2_w3, const void* t2_b3,
    const void* t1_ow, const void* t1_ob, const void* t2_ow, const void* t2_ob,
    const void* masks,
    __bf16* __restrict__ w1s, __bf16* __restrict__ w2s,
    __bf16* __restrict__ wcat2, __bf16* __restrict__ cond_w_bf,
    __bf16* __restrict__ sample_w_bf, __bf16* __restrict__ w3cat_bf,
    float* __restrict__ mask_f, float* __restrict__ pf)
{
  const int bf = *flagp;
  const int S1 = 2048 * 544;   // w1s swizzled
  const int S2 = 2048 * 1152;  // w2s swizzled
  const int S3 = 512 * 512;
  const int S4 = 256 * 512;
  const int S5 = 256 * 1000;
  const int S6 = 512 * 256;
  const int S7 = 10240;
  const int total = S1 + S2 + S3 + S4 + S5 + S6 + S7 + PF_TOTAL;
  for (int idx = blockIdx.x * blockDim.x + threadIdx.x; idx < total;
       idx += gridDim.x * blockDim.x) {
    int i = idx;
    if (i < S1) {
      int e = i & 7, l = (i >> 3) & 63, g = (i >> 9) & 3;
      int grp = i >> 11;               // cgt*17 + kk
      int kk = grp % 17, cgt = grp / 17;
      int colq = l & 15, quad = l >> 4;
      int row = g * 512 + cgt * 16 + colq;
      int k = kk * 32 + quad * 8 + e;
      float v = (k < 512) ? ld_in(w_hh1, (long)row * 512 + k, bf)
              : (k < 525) ? ld_in(w_ih1, (long)row * 13 + (k - 512), bf) : 0.0f;
      w1s[i] = (__bf16)v;
      continue;
    }
    i -= S1;
    if (i < S2) {
      int e = i & 7, l = (i >> 3) & 63, g = (i >> 9) & 3;
      int grp = i >> 11;               // jt*36 + kk
      int kk = grp % 36, jt = grp / 36;
      int colq = l & 15, quad = l >> 4;
      int row = g * 512 + jt * 16 + colq;
      int k = kk * 32 + quad * 8 + e;
      float v = (k < 635) ? ld_in(w_ih2, (long)row * 635 + k, bf)
              : (k < 640) ? 0.0f : ld_in(w_hh2, (long)row * 512 + (k - 640), bf);
      w2s[i] = (__bf16)v;
      continue;
    }
    i -= S2;
    if (i < S3) {
      int r = i >> 9, k = i & 511;
      wcat2[i] = (__bf16)((r < 256) ? ld_in(t1_w2, r * 512 + k, bf)
                                    : ld_in(t2_w2, (r - 256) * 512 + k, bf));
      continue;
    }
    i -= S3;
    if (i < S4) { cond_w_bf[i] = (__bf16)ld_in(cond_w, i, bf); continue; }
    i -= S4;
    if (i < S5) { sample_w_bf[i] = (__bf16)ld_in(sample_w, i, bf); continue; }
    i -= S5;
    if (i < S6) {
      int r = i >> 8, k = i & 255;
      w3cat_bf[i] = (__bf16)((r < 256) ? ld_in(t1_w3, r * 256 + k, bf)
                                       : ld_in(t2_w3, (r - 256) * 256 + k, bf));
      continue;
    }
    i -= S6;
    if (i < S7) { mask_f[i] = ld_in(masks, i, bf); continue; }
    i -= S7;
    {
      int j = i;
      float v;
      if      (j < 2048) v = ld_in(b_ih1, j, bf) + ld_in(b_hh1, j, bf);
      else if (j < 4096) v = ld_in(b_ih2, j - 2048, bf) + ld_in(b_hh2, j - 2048, bf);
      else if (j < 4352) v = ld_in(cond_b, j - 4096, bf);
      else if (j < 4608) v = ld_in(sample_b, j - 4352, bf);
      else if (j < 5120) { int k = j - 4608; v = (k < 256) ? ld_in(t1_b2, k, bf) : ld_in(t2_b2, k - 256, bf); }
      else if (j < 5632) { int k = j - 5120; v = (k < 256) ? ld_in(t1_b3, k, bf) : ld_in(t2_b3, k - 256, bf); }
      else if (j < 5888) v = ld_in(bn1_g, j - 5632, bf);
      else if (j < 6144) v = ld_in(bn1_b, j - 5888, bf);
      else if (j < 6656) v = ld_in(bn2_g, j - 6144, bf);
      else if (j < 7168) v = ld_in(bn2_b, j - 6656, bf);
      else if (j < 7424) v = ld_in(bn3_g, j - 7168, bf);
      else if (j < 7680) v = ld_in(bn3_b, j - 7424, bf);
      else if (j < 8192) { int k = j - 7680; v = (k < 256) ? ld_in(t1_ow, k, bf) : ld_in(t2_ow, k - 256, bf); }
      else v = (j == 8192) ? ld_in(t1_ob, 0, bf) : ld_in(t2_ob, 0, bf);
      pf[j] = v;
    }
  }
}

// ---------------- fused: lstm1 (blocks 0..213, FROZEN loop) + cond-gemm/bn1-
// stats epilogue + sampgemm (1-block-per-row-tile, f32-converting) + featcopy ----
__global__ __launch_bounds__(1024, 4) void fused1_kernel(
    const int* __restrict__ flagp,
    const void* __restrict__ cond1,       // (10240,10,13)
    const __bf16* __restrict__ w1s,       // swizzled (2048x544)
    const float*  __restrict__ bias,      // (2048) = pf+PF_BIAS1
    __bf16* __restrict__ h_out,           // (10272,512) padded
    const void* __restrict__ samples_raw, // sampgemm A (bf16 OR f32, by flag)
    const __bf16* __restrict__ sample_w_bf,
    const float* __restrict__ sampb,      // pf+PF_SAMPB
    __bf16* __restrict__ samp_out,        // Astage+379 (ldc 640)
    const float* __restrict__ mask,
    const void* __restrict__ ops,         // featcopy inputs
    const void* __restrict__ extra,
    __bf16* __restrict__ Astage,          // featcopy dst (stride 640)
    const __bf16* __restrict__ cond_w_bf, // (256,512) cond weights
    const float* __restrict__ condb,      // pf+PF_CONDB
    float* __restrict__ condtmp,          // (10240,256) f32
    float* __restrict__ partial)          // (214,2,256) bn1 partial sums
{
  const int bf = *flagp;
  const int tid = threadIdx.x;

  if (blockIdx.x < L1_BLOCKS) {
    // ================= lstm1 — R12 form, FROZEN =================
    __shared__ __attribute__((aligned(16))) __bf16 hbuf[2][L1_ROWS * LDH1];
    const int wave = tid >> 6;
    const int lane = tid & 63;
    const int colq = lane & 15;
    const int quad = lane >> 4;
    const int r0   = blockIdx.x * L1_ROWS;

    {
      bf16x8 z8 = bzero8();
      for (int i = tid * 8; i < 2 * L1_ROWS * LDH1; i += 1024 * 8)
        *(bf16x8*)&hbuf[0][i] = z8;
    }
    __syncthreads();
    if (tid < L1_ROWS * 8) {           // stage x_0 into buf 0
      int row = tid >> 3, jj = tid & 7;
      int gr = r0 + row;
      if (gr < MROWS) {
        long base = (long)gr * 130;  // t=0
        hbuf[0][row * LDH1 + 512 + jj] = (__bf16)ld_in(cond1, base + jj, bf);
        if (jj < 5) hbuf[0][row * LDH1 + 520 + jj] = (__bf16)ld_in(cond1, base + 8 + jj, bf);
      }
    }
    __syncthreads();

    float c_reg[2][3][4];
#pragma unroll
    for (int a = 0; a < 2; ++a)
#pragma unroll
      for (int b = 0; b < 3; ++b)
#pragma unroll
        for (int r = 0; r < 4; ++r) c_reg[a][b][r] = 0.0f;

    const int jbase = wave * 32;

    float bI[2], bF[2], bG[2], bO[2];
#pragma unroll
    for (int cg = 0; cg < 2; ++cg) {
      const int j = jbase + cg * 16 + colq;
      bI[cg] = bias[j];
      bF[cg] = bias[512 + j];
      bG[cg] = bias[1024 + j];
      bO[cg] = bias[1536 + j];
    }

#pragma unroll 1
    for (int t = 0; t < 10; ++t) {
      const __bf16* hcur = hbuf[t & 1];
      __bf16* hnxt = hbuf[(t + 1) & 1];
#pragma unroll
      for (int cg = 0; cg < 2; ++cg) {
        const int jc = jbase + cg * 16;
        f32x4 acc[3][4];
#pragma unroll
        for (int a = 0; a < 3; ++a)
#pragma unroll
          for (int g = 0; g < 4; ++g)
#pragma unroll
            for (int r = 0; r < 4; ++r) acc[a][g][r] = 0.0f;

        const __bf16* wp = w1s + ((size_t)(wave * 2 + cg) * 17 * 4 * 512) + (lane << 3);
#pragma unroll 1
        for (int kk = 0; kk < 17; ++kk) {
          const int kof = (kk << 5) + (quad << 3);
          bf16x8 af[3];
#pragma unroll
          for (int rt = 0; rt < 3; ++rt)
            af[rt] = *(const bf16x8*)&hcur[(rt * 16 + colq) * LDH1 + kof];
          bf16x8 bfr[4];
#pragma unroll
          for (int g = 0; g < 4; ++g)
            bfr[g] = *(const bf16x8*)&wp[(kk * 4 + g) << 9];
#pragma unroll
          for (int g = 0; g < 4; ++g)
#pragma unroll
            for (int rt = 0; rt < 3; ++rt)
              acc[rt][g] = __builtin_amdgcn_mfma_f32_16x16x32_bf16(af[rt], bfr[g], acc[rt][g], 0, 0, 0);
        }
#pragma unroll
        for (int rt = 0; rt < 3; ++rt)
#pragma unroll
          for (int r = 0; r < 4; ++r) {
            float c = fsig(acc[rt][1][r] + bF[cg]) * c_reg[cg][rt][r]
                    + fsig(acc[rt][0][r] + bI[cg]) * ftanh(acc[rt][2][r] + bG[cg]);
            c_reg[cg][rt][r] = c;
            float h = fsig(acc[rt][3][r] + bO[cg]) * ftanh(c);
            hnxt[(rt * 16 + quad * 4 + r) * LDH1 + jc + colq] = (__bf16)h;
          }
      }
      if (t < 9 && tid < L1_ROWS * 8) {   // stage x_{t+1} into next buffer
        int row = tid >> 3, jj = tid & 7;
        int gr = r0 + row;
        if (gr < MROWS) {
          long base = ((long)gr * 10 + (t + 1)) * 13;
          hnxt[row * LDH1 + 512 + jj] = (__bf16)ld_in(cond1, base + jj, bf);
          if (jj < 5) hnxt[row * LDH1 + 520 + jj] = (__bf16)ld_in(cond1, base + 8 + jj, bf);
        }
      }
      __syncthreads();
    }

    // final h is in buffer 0 (t=10 even)
    for (int i = tid; i < L1_ROWS * 64; i += 1024) {
      int row = i >> 6;
      int cb  = (i & 63) << 3;
      *(bf16x8*)&h_out[(size_t)(r0 + row) * 512 + cb] = *(const bf16x8*)&hbuf[0][row * LDH1 + cb];
    }

    // ===== cond = relu(h @ cond_w^T + condb) + bn1 partials (R22, FROZEN) ==
    {
      const int ct = wave;          // 0..15 -> cols ct*16 + colq
      f32x4 cacc[3];
#pragma unroll
      for (int rt = 0; rt < 3; ++rt)
#pragma unroll
        for (int r = 0; r < 4; ++r) cacc[rt][r] = 0.0f;

      const __bf16* wb = cond_w_bf + (size_t)(ct * 16 + colq) * 512;
#pragma unroll 1
      for (int kk = 0; kk < 16; ++kk) {
        const int kof = (kk << 5) + (quad << 3);
        bf16x8 bfr = *(const bf16x8*)&wb[kof];
#pragma unroll
        for (int rt = 0; rt < 3; ++rt) {
          bf16x8 af = *(const bf16x8*)&hbuf[0][(rt * 16 + colq) * LDH1 + kof];
          cacc[rt] = __builtin_amdgcn_mfma_f32_16x16x32_bf16(af, bfr, cacc[rt], 0, 0, 0);
        }
      }
      const int col = ct * 16 + colq;
      const float bv = condb[col];
      float s1 = 0.0f, s2 = 0.0f;
#pragma unroll
      for (int rt = 0; rt < 3; ++rt)
#pragma unroll
        for (int r = 0; r < 4; ++r) {
          const int lrow = rt * 16 + quad * 4 + r;
          const int grow = r0 + lrow;
          float v = fmaxf(cacc[rt][r] + bv, 0.0f);
          if (grow < MROWS) {
            condtmp[(size_t)grow * 256 + col] = v;
            s1 += v;
            s2 += v * v;
          }
        }
      s1 += __shfl_xor(s1, 16); s2 += __shfl_xor(s2, 16);
      s1 += __shfl_xor(s1, 32); s2 += __shfl_xor(s2, 32);
      if (quad == 0) {
        partial[(size_t)(2 * blockIdx.x) * 256 + col]     = s1;
        partial[(size_t)(2 * blockIdx.x + 1) * 256 + col] = s2;
      }
    }
    return;
  }

  if (blockIdx.x < FEAT_BASE) {
    // ====== sampgemm R24: 1 block per 64-row tile; full 64x256 output ======
    // 16 waves = 4 row-tiles (rt) x 4 col-groups (cg). Per kk: 1 A-frag
    // (f32->bf16 on load; waves sharing rt hit L1) x 4 B-frags x 4 MFMAs.
    const int by   = blockIdx.x - SAMP_BASE;  // 0..159
    const int wave = tid >> 6;
    const int lane = tid & 63;
    const int colq = lane & 15;
    const int quad = lane >> 4;
    const int rt = wave & 3;                  // row tile (16 rows)
    const int cg = wave >> 2;                 // col group (64 cols)
    const int m0 = by * 64 + rt * 16;
    const int n0 = cg * 64;
    const int K = 1000;

    f32x4 acc[4];
#pragma unroll
    for (int j = 0; j < 4; ++j)
#pragma unroll
      for (int r = 0; r < 4; ++r) acc[j][r] = 0.0f;

    for (int kk = 0; kk < 32; ++kk) {
      const int kof = (kk << 5) + (quad << 3);
      bf16x8 a0, b0, b1, b2, b3;
      if (kof < K) {
        if (bf) {
          a0 = *(const bf16x8*)&((const __bf16*)samples_raw)[(size_t)(m0 + colq) * 1000 + kof];
        } else {
          const float* p0 = &((const float*)samples_raw)[(size_t)(m0 + colq) * 1000 + kof];
#pragma unroll
          for (int e = 0; e < 8; ++e) a0[e] = (__bf16)p0[e];
        }
        b0 = *(const bf16x8*)&sample_w_bf[(size_t)(n0 + 0  + colq) * 1000 + kof];
        b1 = *(const bf16x8*)&sample_w_bf[(size_t)(n0 + 16 + colq) * 1000 + kof];
        b2 = *(const bf16x8*)&sample_w_bf[(size_t)(n0 + 32 + colq) * 1000 + kof];
        b3 = *(const bf16x8*)&sample_w_bf[(size_t)(n0 + 48 + colq) * 1000 + kof];
      } else {
        a0 = bzero8(); b0 = a0; b1 = a0; b2 = a0; b3 = a0;
      }
      acc[0] = __builtin_amdgcn_mfma_f32_16x16x32_bf16(a0, b0, acc[0], 0, 0, 0);
      acc[1] = __builtin_amdgcn_mfma_f32_16x16x32_bf16(a0, b1, acc[1], 0, 0, 0);
      acc[2] = __builtin_amdgcn_mfma_f32_16x16x32_bf16(a0, b2, acc[2], 0, 0, 0);
      acc[3] = __builtin_amdgcn_mfma_f32_16x16x32_bf16(a0, b3, acc[3], 0, 0, 0);
    }
#pragma unroll
    for (int j = 0; j < 4; ++j) {
      const int col = n0 + j * 16 + colq;
      const float bv = sampb[col];
#pragma unroll
      for (int r = 0; r < 4; ++r) {
        const int row = m0 + quad * 4 + r;
        float v = fmaxf(acc[j][r] + bv, 0.0f) * mask[row];
        samp_out[(size_t)row * 640 + col] = (__bf16)v;
      }
    }
    return;
  }

  // ================= featcopy (grid-stride over 10240*128) =================
  for (int idx = (blockIdx.x - FEAT_BASE) * 1024 + tid; idx < 10240 * 128;
       idx += 40 * 1024) {
    int m = idx >> 7, c = idx & 127;
    float v; int col;
    if (c < 15)       { v = ld_in(ops, (long)m * 15 + c, bf);            col = c; }
    else if (c < 123) { v = ld_in(extra, (long)m * 108 + (c - 15), bf);  col = c; }
    else              { v = 0.0f;                                        col = 512 + c; } // 635..639
    Astage[(size_t)m * 640 + col] = (__bf16)v;
  }
}

// ---------------- bn1 stats2: wave-per-column over 214 partials ----------------
__global__ void bn1stats2_kernel(const float* __restrict__ partial,
                                 float* __restrict__ stats)
{
  const int col  = blockIdx.x * 4 + (threadIdx.x >> 6); // 0..255
  const int lane = threadIdx.x & 63;
  float s = 0.0f, sq = 0.0f;
  for (int b = lane; b < L1_BLOCKS; b += 64) {
    s  += partial[(size_t)(2 * b) * 256 + col];
    sq += partial[(size_t)(2 * b + 1) * 256 + col];
  }
#pragma unroll
  for (int off = 32; off > 0; off >>= 1) {
    s  += __shfl_down(s, off);
    sq += __shfl_down(sq, off);
  }
  if (lane == 0) {
    float mean = s * (1.0f / 10240.0f);
    float var  = sq * (1.0f / 10240.0f) - mean * mean;
    stats[col]       = mean;
    stats[256 + col] = rsqrtf(fmaxf(var, 0.0f) + 1e-5f);
  }
}

// ---------------- generic MFMA GEMM: out = act(A @ W^T + bias) [* mask] ----------------
template<int ACT, int OUTBF, int MASKED>
__global__ __launch_bounds__(256, 4) void gemm_kernel(
    const __bf16* __restrict__ A, int lda,
    const __bf16* __restrict__ W, int ldw,
    const float* __restrict__ bias,
    float* __restrict__ outf, __bf16* __restrict__ outb, int ldc,
    const float* __restrict__ mask, int K)
{
  const int tid  = threadIdx.x;
  const int wave = tid >> 6;
  const int lane = tid & 63;
  const int colq = lane & 15;
  const int quad = lane >> 4;
  const int m0 = blockIdx.y * 64 + (wave >> 1) * 32;
  const int n0 = blockIdx.x * 64 + (wave & 1) * 32;

  f32x4 acc[2][2];
#pragma unroll
  for (int a = 0; a < 2; ++a)
#pragma unroll
    for (int b = 0; b < 2; ++b)
#pragma unroll
      for (int r = 0; r < 4; ++r) acc[a][b][r] = 0.0f;

  const int nk = (K + 31) >> 5;
  for (int kk = 0; kk < nk; ++kk) {
    const int kof = (kk << 5) + (quad << 3);
    bf16x8 a0, a1, b0, b1;
    if (kof < K) {
      a0 = *(const bf16x8*)&A[(size_t)(m0 + colq) * lda + kof];
      a1 = *(const bf16x8*)&A[(size_t)(m0 + 16 + colq) * lda + kof];
      b0 = *(const bf16x8*)&W[(size_t)(n0 + colq) * ldw + kof];
      b1 = *(const bf16x8*)&W[(size_t)(n0 + 16 + colq) * ldw + kof];
    } else {
      a0 = bzero8(); a1 = a0; b0 = a0; b1 = a0;
    }
    acc[0][0] = __builtin_amdgcn_mfma_f32_16x16x32_bf16(a0, b0, acc[0][0], 0, 0, 0);
    acc[0][1] = __builtin_amdgcn_mfma_f32_16x16x32_bf16(a0, b1, acc[0][1], 0, 0, 0);
    acc[1][0] = __builtin_amdgcn_mfma_f32_16x16x32_bf16(a1, b0, acc[1][0], 0, 0, 0);
    acc[1][1] = __builtin_amdgcn_mfma_f32_16x16x32_bf16(a1, b1, acc[1][1], 0, 0, 0);
  }
#pragma unroll
  for (int ai = 0; ai < 2; ++ai)
#pragma unroll
    for (int bi = 0; bi < 2; ++bi) {
      const int col = n0 + bi * 16 + colq;
      const float bv = bias[col];
#pragma unroll
      for (int r = 0; r < 4; ++r) {
        const int row = m0 + ai * 16 + quad * 4 + r;
        float v = acc[ai][bi][r] + bv;
        if (ACT) v = fmaxf(v, 0.0f);
        if (MASKED) v *= mask[row];
        if (OUTBF) outb[(size_t)row * ldc + col] = (__bf16)v;
        else       outf[(size_t)row * ldc + col] = v;
      }
    }
}

// ---------------- merged w3 head GEMMs: both heads in one launch ----------------
// grid (8,8): which = bx>>2, n-tile = bx&3. out = relu(t @ w3^T + b3) per head.
__global__ __launch_bounds__(256, 4) void w3gemm_kernel(
    const __bf16* __restrict__ tmp2,    // (512,512), head h uses cols h*256..
    const __bf16* __restrict__ w3cat,   // (512,256) [t1;t2]
    const float* __restrict__ b3,       // pf+PF_B3CAT (512)
    __bf16* __restrict__ tmp3)          // (512,512), head h writes cols h*256..
{
  const int which = blockIdx.x >> 2;
  const int bx    = blockIdx.x & 3;
  const __bf16* A = tmp2 + which * 256;
  const __bf16* W = w3cat + (size_t)which * 256 * 256;
  const float* bias = b3 + which * 256;
  __bf16* outb = tmp3 + which * 256;
  const int lda = 512, ldw = 256, ldc = 512;

  const int tid  = threadIdx.x;
  const int wave = tid >> 6;
  const int lane = tid & 63;
  const int colq = lane & 15;
  const int quad = lane >> 4;
  const int m0 = blockIdx.y * 64 + (wave >> 1) * 32;
  const int n0 = bx * 64 + (wave & 1) * 32;

  f32x4 acc[2][2];
#pragma unroll
  for (int a = 0; a < 2; ++a)
#pragma unroll
    for (int b = 0; b < 2; ++b)
#pragma unroll
      for (int r = 0; r < 4; ++r) acc[a][b][r] = 0.0f;

  for (int kk = 0; kk < 8; ++kk) {
    const int kof = (kk << 5) + (quad << 3);
    bf16x8 a0 = *(const bf16x8*)&A[(size_t)(m0 + colq) * lda + kof];
    bf16x8 a1 = *(const bf16x8*)&A[(size_t)(m0 + 16 + colq) * lda + kof];
    bf16x8 b0 = *(const bf16x8*)&W[(size_t)(n0 + colq) * ldw + kof];
    bf16x8 b1 = *(const bf16x8*)&W[(size_t)(n0 + 16 + colq) * ldw + kof];
    acc[0][0] = __builtin_amdgcn_mfma_f32_16x16x32_bf16(a0, b0, acc[0][0], 0, 0, 0);
    acc[0][1] = __builtin_amdgcn_mfma_f32_16x16x32_bf16(a0, b1, acc[0][1], 0, 0, 0);
    acc[1][0] = __builtin_amdgcn_mfma_f32_16x16x32_bf16(a1, b0, acc[1][0], 0, 0, 0);
    acc[1][1] = __builtin_amdgcn_mfma_f32_16x16x32_bf16(a1, b1, acc[1][1], 0, 0, 0);
  }
#pragma unroll
  for (int ai = 0; ai < 2; ++ai)
#pragma unroll
    for (int bi = 0; bi < 2; ++bi) {
      const int col = n0 + bi * 16 + colq;
      const float bv = bias[col];
#pragma unroll
      for (int r = 0; r < 4; ++r) {
        const int row = m0 + ai * 16 + quad * 4 + r;
        float v = fmaxf(acc[ai][bi][r] + bv, 0.0f);
        outb[(size_t)row * ldc + col] = (__bf16)v;
      }
    }
}

// ---------------- fused tree level: quarter-K gather + GEMM(K=1152) + cell ----------
// R18 form (FROZEN): 1024 thr (16 waves), grid (32,8). kq = wave>>2, wv = wave&3.
__global__ __launch_bounds__(1024, 4) void treelvl_kernel(
    const __bf16* __restrict__ Alvl,    // (512,640) level features
    const __bf16* __restrict__ w2s,     // swizzled (2048x1152)
    const float* __restrict__ bias,     // 2048
    const int* __restrict__ mapping,    // level's (2,512)
    const __bf16* __restrict__ h_src, const float* __restrict__ c_src,
    __bf16* __restrict__ h_dst, float* __restrict__ c_dst,
    float* __restrict__ h_f32, int first, int last)
{
  __shared__ float red[3][16 * 256];   // 3 slots x 16KB, [g*4+r][wv*64+lane]
  const int tid  = threadIdx.x;
  const int wave = tid >> 6;          // 0..15
  const int lane = tid & 63;
  const int colq = lane & 15;
  const int quad = lane >> 4;
  const int wv   = wave & 3;          // row sub-tile 0..3
  const int kq   = wave >> 2;         // K quarter 0..3
  const int jt = blockIdx.x;
  const int mt = blockIdx.y;
  const int rowA = mt * 64 + wv * 16 + colq;

  const __bf16* wbase = w2s + (size_t)jt * 36 * 4 * 512 + (lane << 3);

  f32x4 acc[4];
#pragma unroll
  for (int g = 0; g < 4; ++g)
#pragma unroll
    for (int r = 0; r < 4; ++r) acc[g][r] = 0.0f;

  if (kq < 2) {
    // ---- feature part of K: kq0 -> kk 0..9, kq1 -> kk 10..19 ----
    const __bf16* arow = Alvl + (size_t)rowA * 640;
    const int kb = kq * 10;
#pragma unroll 2
    for (int ki = 0; ki < 10; ++ki) {
      const int kk = kb + ki;
      const int kof = (kk << 5) + (quad << 3);
      bf16x8 afr = *(const bf16x8*)&arow[kof];
      bf16x8 b0 = *(const bf16x8*)&wbase[(kk * 4 + 0) << 9];
      bf16x8 b1 = *(const bf16x8*)&wbase[(kk * 4 + 1) << 9];
      bf16x8 b2 = *(const bf16x8*)&wbase[(kk * 4 + 2) << 9];
      bf16x8 b3 = *(const bf16x8*)&wbase[(kk * 4 + 3) << 9];
      acc[0] = __builtin_amdgcn_mfma_f32_16x16x32_bf16(afr, b0, acc[0], 0, 0, 0);
      acc[1] = __builtin_amdgcn_mfma_f32_16x16x32_bf16(afr, b1, acc[1], 0, 0, 0);
      acc[2] = __builtin_amdgcn_mfma_f32_16x16x32_bf16(afr, b2, acc[2], 0, 0, 0);
      acc[3] = __builtin_amdgcn_mfma_f32_16x16x32_bf16(afr, b3, acc[3], 0, 0, 0);
    }
  } else {
    // ---- gathered-h part of K: kq2 -> kk 20..27, kq3 -> kk 28..35 ----
    int i0 = 0, i1 = 0;
    if (!first) { i0 = mapping[rowA]; i1 = mapping[512 + rowA]; }
    const float s0 = (i0 > 0) ? 0.5f : 0.0f;
    const float s1 = (i1 > 0) ? 0.5f : 0.0f;
    const __bf16* h0p = h_src + (size_t)((i0 > 0 ? i0 : 1) - 1) * 512;
    const __bf16* h1p = h_src + (size_t)((i1 > 0 ? i1 : 1) - 1) * 512;
    const int kb = 20 + (kq - 2) * 8;
#pragma unroll 2
    for (int ki = 0; ki < 8; ++ki) {
      const int kk = kb + ki;
      const int kh = ((kk - 20) << 5) + (quad << 3);
      bf16x8 v0 = *(const bf16x8*)&h0p[kh];
      bf16x8 v1 = *(const bf16x8*)&h1p[kh];
      bf16x8 afr;
#pragma unroll
      for (int e = 0; e < 8; ++e)
        afr[e] = (__bf16)((float)v0[e] * s0 + (float)v1[e] * s1);
      bf16x8 b0 = *(const bf16x8*)&wbase[(kk * 4 + 0) << 9];
      bf16x8 b1 = *(const bf16x8*)&wbase[(kk * 4 + 1) << 9];
      bf16x8 b2 = *(const bf16x8*)&wbase[(kk * 4 + 2) << 9];
      bf16x8 b3 = *(const bf16x8*)&wbase[(kk * 4 + 3) << 9];
      acc[0] = __builtin_amdgcn_mfma_f32_16x16x32_bf16(afr, b0, acc[0], 0, 0, 0);
      acc[1] = __builtin_amdgcn_mfma_f32_16x16x32_bf16(afr, b1, acc[1], 0, 0, 0);
      acc[2] = __builtin_amdgcn_mfma_f32_16x16x32_bf16(afr, b2, acc[2], 0, 0, 0);
      acc[3] = __builtin_amdgcn_mfma_f32_16x16x32_bf16(afr, b3, acc[3], 0, 0, 0);
    }
  }

  if (kq > 0) {
    // stash partials: scalar f32, lane-consecutive -> conflict-free
    float* rp = red[kq - 1];
    const int base = wv * 64 + lane;
#pragma unroll
    for (int g = 0; g < 4; ++g)
#pragma unroll
      for (int r = 0; r < 4; ++r)
        rp[(g * 4 + r) * 256 + base] = acc[g][r];
  }
  __syncthreads();
  if (kq != 0) return;

  // kq0: combine 3 partials, then the unchanged epilogue
  {
    const int base = wv * 64 + lane;
#pragma unroll
    for (int s = 0; s < 3; ++s) {
      const float* rp = red[s];
#pragma unroll
      for (int g = 0; g < 4; ++g)
#pragma unroll
        for (int r = 0; r < 4; ++r)
          acc[g][r] += rp[(g * 4 + r) * 256 + base];
    }
  }

  // epilogue: i,f,g,o -> c,h
  const int j = jt * 16 + colq;
  const float bi  = bias[j];
  const float bff = bias[512 + j];
  const float bg  = bias[1024 + j];
  const float bo  = bias[1536 + j];
#pragma unroll
  for (int r = 0; r < 4; ++r) {
    const int mrow = mt * 64 + wv * 16 + quad * 4 + r;
    float ci = 0.0f;
    if (!first) {
      int a0 = mapping[mrow], a1 = mapping[512 + mrow];
      if (a0 > 0) ci += c_src[(size_t)(a0 - 1) * 512 + j];
      if (a1 > 0) ci += c_src[(size_t)(a1 - 1) * 512 + j];
      ci *= 0.5f;
    }
    float c = fsig(acc[1][r] + bff) * ci + fsig(acc[0][r] + bi) * ftanh(acc[2][r] + bg);
    float h = fsig(acc[3][r] + bo) * ftanh(c);
    h_dst[(size_t)mrow * 512 + j] = (__bf16)h;
    c_dst[(size_t)mrow * 512 + j] = c;
    if (last) h_f32[(size_t)mrow * 512 + j] = h;
  }
}

// ---------------- batchnorm helpers ----------------
__global__ void stats1_kernel(const float* __restrict__ in, int ld, int N,
                              int rows_per_blk, float* __restrict__ partial)
{
  int b = blockIdx.x;
  int r0 = b * rows_per_blk;
  for (int c = threadIdx.x; c < N; c += blockDim.x) {
    float s = 0.0f, sq = 0.0f;
    for (int r = 0; r < rows_per_blk; ++r) {
      float v = in[(size_t)(r0 + r) * ld + c];
      s += v; sq += v * v;
    }
    partial[(size_t)(2 * b) * N + c] = s;
    partial[(size_t)(2 * b + 1) * N + c] = sq;
  }
}

__global__ void stats2_kernel(const float* __restrict__ partial, int nb, int N,
                              float invM, float* __restrict__ stats)
{
  int c = blockIdx.x * blockDim.x + threadIdx.x;
  if (c >= N) return;
  float s = 0.0f, sq = 0.0f;
  for (int b = 0; b < nb; ++b) {
    s  += partial[(size_t)(2 * b) * N + c];
    sq += partial[(size_t)(2 * b + 1) * N + c];
  }
  float mean = s * invM;
  float var  = sq * invM - mean * mean;
  stats[c]     = mean;
  stats[N + c] = rsqrtf(fmaxf(var, 0.0f) + 1e-5f);
}

__global__ void norm_kernel(const float* __restrict__ in, int ldin,
                            const float* __restrict__ stats, int N, int cshift, int gmask,
                            const float* __restrict__ g, const float* __restrict__ b,
                            __bf16* __restrict__ outp, int ldc, int total)
{
  for (int idx = blockIdx.x * blockDim.x + threadIdx.x; idx < total;
       idx += gridDim.x * blockDim.x) {
    int row = idx >> cshift;
    int c = idx & (N - 1);
    float v = (in[(size_t)row * ldin + c] - stats[c]) * stats[N + c];
    int gi = c & gmask;
    v = v * g[gi] + b[gi];
    outp[(size_t)row * ldc + c] = (__bf16)v;
  }
}

// ---------------- output heads: one wave per output ----------------
__global__ void head_kernel(const int* __restrict__ flagp,
                            const __bf16* __restrict__ tmp3,
                            const float* __restrict__ pf,
                            void* __restrict__ outp)
{
  const int bf = *flagp;
  const int gw   = blockIdx.x * 4 + (threadIdx.x >> 6);  // 0..1023
  const int lane = threadIdx.x & 63;
  const int which = gw >> 9;
  const int n     = gw & 511;
  const __bf16* row = tmp3 + (size_t)n * 512 + which * 256;
  const float* ow = pf + PF_OW + which * 256;
  float s = 0.0f;
#pragma unroll
  for (int i = 0; i < 4; ++i) {
    const int k = lane + 64 * i;
    s += (float)row[k] * ow[k];
  }
#pragma unroll
  for (int off = 32; off > 0; off >>= 1)
    s += __shfl_down(s, off);
  if (lane == 0) {
    float v = fsig(s + pf[PF_OB + which]);
    if (bf) ((__bf16*)outp)[gw] = (__bf16)v;
    else    ((float*)outp)[gw]  = v;
  }
}

// ---------------- launch ----------------
extern "C" void kernel_launch(void* const* d_in, const int* in_sizes, int n_in,
                              void* d_out, int out_size, void* d_ws, size_t ws_size,
                              hipStream_t stream) {
  const void* operators       = d_in[0];
  const void* extra_infos     = d_in[1];
  const void* condition1s     = d_in[2];
  const void* samples         = d_in[4];
  const void* condition_masks = d_in[5];
  const int*  mapping         = (const int*)d_in[6];
  (void)in_sizes; (void)n_in; (void)out_size; (void)ws_size;

  char* ws = (char*)d_ws;
  size_t off = 0;
  auto alloc = [&](size_t bytes) -> void* {
    void* p = ws + off;
    off += (bytes + 255) & ~(size_t)255;
    return p;
  };
  int*    flag     = (int*)   alloc(256);
  __bf16* w1s      = (__bf16*)alloc((size_t)2048 * 544 * 2);
  __bf16* w2s      = (__bf16*)alloc((size_t)2048 * 1152 * 2);
  __bf16* wcat2    = (__bf16*)alloc(512 * 512 * 2);
  __bf16* cond_w_bf   = (__bf16*)alloc(256 * 512 * 2);
  __bf16* sample_w_bf = (__bf16*)alloc(256 * 1000 * 2);
  __bf16* w3cat_bf    = (__bf16*)alloc(512 * 256 * 2);
  float*  mask_f   = (float*) alloc(10240 * 4);
  float*  pf       = (float*) alloc(PF_TOTAL * 4);
  __bf16* h_last   = (__bf16*)alloc((size_t)10272 * 512 * 2);
  float*  condtmp  = (float*) alloc((size_t)10240 * 256 * 4);
  __bf16* Astage   = (__bf16*)alloc((size_t)20 * 512 * 640 * 2);
  __bf16* hs0      = (__bf16*)alloc(512 * 512 * 2);
  __bf16* hs1      = (__bf16*)alloc(512 * 512 * 2);
  float*  cs0      = (float*) alloc(512 * 512 * 4);
  float*  cs1      = (float*) alloc(512 * 512 * 4);
  float*  h_f32    = (float*) alloc(512 * 512 * 4);
  __bf16* zbuf     = (__bf16*)alloc(512 * 512 * 2);
  float*  tmp1     = (float*) alloc(512 * 512 * 4);
  __bf16* tmp2     = (__bf16*)alloc(512 * 512 * 2);
  __bf16* tmp3     = (__bf16*)alloc(512 * 512 * 2);
  float*  partial  = (float*) alloc((size_t)214 * 2 * 256 * 4 + 8 * 2 * 512 * 4);
  float*  statsb   = (float*) alloc(2 * 512 * 4);

  detect_kernel<<<1, 64, 0, stream>>>((const unsigned*)condition_masks, flag);
  prep_kernel<<<4096, 256, 0, stream>>>(flag,
      d_in[7], d_in[8], d_in[9], d_in[10],
      d_in[17], d_in[18], d_in[19], d_in[20],
      d_in[23], d_in[25], d_in[24], d_in[26],
      d_in[13], d_in[14], d_in[11], d_in[12],
      d_in[15], d_in[16], d_in[21], d_in[22],
      d_in[27], d_in[28],
      d_in[29], d_in[30], d_in[31], d_in[32],
      d_in[33], d_in[34], d_in[35], d_in[36],
      condition_masks,
      w1s, w2s, wcat2, cond_w_bf, sample_w_bf, w3cat_bf, mask_f, pf);

  // lstm1 (+cond gemm + bn1 partial stats) + sampgemm (1-block-per-tile,
  // f32-converting) + featcopy in one launch
  fused1_kernel<<<FUSED_BLOCKS, 1024, 0, stream>>>(flag,
      condition1s, w1s, pf + PF_BIAS1, h_last,
      samples, sample_w_bf, pf + PF_SAMPB, Astage + 379, mask_f,
      operators, extra_infos, Astage,
      cond_w_bf, pf + PF_CONDB, condtmp, partial);

  // bn1: wave-per-column stats over the 214 partials, then normalize
  bn1stats2_kernel<<<64, 256, 0, stream>>>(partial, statsb);
  norm_kernel<<<2560, 256, 0, stream>>>(condtmp, 256, statsb, 256, 8, 255,
      pf + PF_BN1G, pf + PF_BN1B, Astage + 123, 640, 10240 * 256);

  // tree: lvl 19 (zero state) down to 0; ping-pong state by level parity
  for (int lvl = 19; lvl >= 0; --lvl) {
    __bf16* hd = (lvl & 1) ? hs1 : hs0;
    float*  cd = (lvl & 1) ? cs1 : cs0;
    const __bf16* hsrc = (lvl & 1) ? hs0 : hs1;
    const float*  csrc = (lvl & 1) ? cs0 : cs1;
    treelvl_kernel<<<dim3(32,8), 1024, 0, stream>>>(
        Astage + (size_t)lvl * 512 * 640, w2s, pf + PF_BIAS2,
        mapping + lvl * 1024, hsrc, csrc, hd, cd, h_f32,
        (lvl == 19) ? 1 : 0, (lvl == 0) ? 1 : 0);
  }

  // z = bn2(hid)
  stats1_kernel<<<8, 256, 0, stream>>>(h_f32, 512, 512, 64, partial);
  stats2_kernel<<<2, 256, 0, stream>>>(partial, 8, 512, 1.0f / 512.0f, statsb);
  norm_kernel<<<256, 256, 0, stream>>>(h_f32, 512, statsb, 512, 9, 511,
      pf + PF_BN2G, pf + PF_BN2B, zbuf, 512, 512 * 512);

  // [t1|t2] = bn3(relu(z @ [t1_w2;t2_w2]^T + b))
  gemm_kernel<1,0,0><<<dim3(8,8), 256, 0, stream>>>(zbuf, 512, wcat2, 512,
      pf + PF_BCAT2, tmp1, nullptr, 512, nullptr, 512);
  stats1_kernel<<<8, 256, 0, stream>>>(tmp1, 512, 512, 64, partial);
  stats2_kernel<<<2, 256, 0, stream>>>(partial, 8, 512, 1.0f / 512.0f, statsb);
  norm_kernel<<<256, 256, 0, stream>>>(tmp1, 512, statsb, 512, 9, 255,
      pf + PF_BN3G, pf + PF_BN3B, tmp2, 512, 512 * 512);

  // relu(t @ w3^T + b3) for both heads in ONE launch
  w3gemm_kernel<<<dim3(8,8), 256, 0, stream>>>(tmp2, w3cat_bf, pf + PF_B3CAT, tmp3);

  head_kernel<<<256, 256, 0, stream>>>(flag, tmp3, pf, d_out);
}